// Round 6
// baseline (152.597 us; speedup 1.0000x reference)
//
#include <hip/hip_runtime.h>

constexpr int NB   = 2;
constexpr int CIN  = 128;
constexpr int TT   = 8;
constexpr int HH   = 56;
constexpr int WW   = 56;
constexpr int S    = TT * HH * WW;      // 25088
constexpr int DK   = 16;
constexpr int DV   = 128;
constexpr int TAPS = 147;               // 3*7*7
constexpr int NOUT = DK + DV;           // 144
// padded channel-last v: [b][t:10][h:62][w:62][c:128]
constexpr int VPT = 10, VPH = 62, VPW = 62;
constexpr int PCELLS = NB * VPT * VPH * VPW;   // 76880 padded cells
constexpr int WSTR = 149;               // weff LDS stride (149 mod 32 = 21, odd -> conflict-free)
constexpr float EPSf = 1e-6f;

// ---------------------------------------------------------------------------
// Wp[o][c] -> Wpt[c][144]
// ---------------------------------------------------------------------------
__global__ __launch_bounds__(256) void k_twp(
    const float* __restrict__ Wp, float* __restrict__ Wpt)
{
    int i = blockIdx.x * 256 + threadIdx.x;
    if (i >= CIN * NOUT) return;
    int c = i / NOUT, o = i - c * NOUT;
    Wpt[i] = Wp[o * CIN + c];
}

// ---------------------------------------------------------------------------
// Zero only the halo of vcl (13.7 MB instead of 39.4 MB memset).
// ---------------------------------------------------------------------------
__global__ __launch_bounds__(256) void k_zero(float* __restrict__ vcl)
{
    int gid  = blockIdx.x * 256 + threadIdx.x;
    int cell = gid >> 5;
    int ch4  = gid & 31;
    if (cell >= PCELLS) return;
    int rb = cell;
    int wp = rb % VPW; rb /= VPW;
    int hp = rb % VPH; rb /= VPH;
    int tp = rb % VPT;
    if (tp >= 1 && tp <= 8 && hp >= 3 && hp <= 58 && wp >= 3 && wp <= 58) return;
    float4 z = {0.f, 0.f, 0.f, 0.f};
    *reinterpret_cast<float4*>(vcl + (size_t)cell * 128 + ch4 * 4) = z;
}

// ---------------------------------------------------------------------------
// k_proj: block = 576 threads = 9 waves, all sharing one 64-position x tile
// (L1 reuse). Wave og=0 computes q[16]; waves og=1..8 compute 16 v-channels
// each. (unchanged from R5 — VGPR 32, no spill)
// ---------------------------------------------------------------------------
__global__ __launch_bounds__(576) void k_proj(
    const float* __restrict__ x, const float* __restrict__ Wpt,
    float* __restrict__ qn, float* __restrict__ vcl)
{
    __shared__ float svl[9 * 64];
    int tid = threadIdx.x;
    int pos = tid & 63;
    int og  = __builtin_amdgcn_readfirstlane(tid >> 6);   // 0..8, wave-uniform
    int gid = blockIdx.x * 64 + pos;                      // < NB*S (784*64)
    int b = gid / S, p = gid - b * S;

    const float* xp = x + (size_t)b * CIN * S + p;
    const float* wr = Wpt + og * 16;

    float acc[16];
#pragma unroll
    for (int o = 0; o < 16; ++o) acc[o] = 0.f;

#pragma unroll 4
    for (int c = 0; c < CIN; ++c) {
        float xc = xp[(size_t)c * S];
        const float* wc = wr + c * NOUT;
#pragma unroll
        for (int o = 0; o < 16; ++o)
            acc[o] = fmaf(xc, wc[o], acc[o]);
    }

    float ss = 0.f;
#pragma unroll
    for (int o = 0; o < 16; ++o) ss += acc[o] * acc[o];
    svl[og * 64 + pos] = ss;
    __syncthreads();
    float ssv = 0.f;
#pragma unroll
    for (int g = 1; g < 9; ++g) ssv += svl[g * 64 + pos];
    float vsc = 1.0f / sqrtf(ssv + EPSf);

    if (og == 0) {
        float qsc = 1.0f / sqrtf(ss + EPSf);
#pragma unroll
        for (int o = 0; o < DK; ++o)
            qn[((size_t)b * DK + o) * S + p] = acc[o] * qsc;
    } else {
        int t  = p / (HH * WW);
        int hw = p - t * (HH * WW);
        int h  = hw / WW;
        int w  = hw - h * WW;
        float* vd = vcl
            + (((size_t)(b * VPT + t + 1) * VPH + (h + 3)) * VPW + (w + 3)) * 128
            + (og - 1) * 16;
#pragma unroll
        for (int j = 0; j < 16; j += 4) {
            float4 v4 = {acc[j] * vsc, acc[j + 1] * vsc,
                         acc[j + 2] * vsc, acc[j + 3] * vsc};
            *reinterpret_cast<float4*>(vd + j) = v4;
        }
    }
}

// ---------------------------------------------------------------------------
// k_out: block = (b,t,h) row, 512 threads = 8 waves (was 4).
//   Same 36.9 KB LDS -> 4 blocks/CU -> 32 waves/CU ceiling (was 16).
//   Phase 3: wt = tid>>6 (8 tiles x 7 outputs), cc = tid&63 (64 x 2 ch):
//   weff reads are wave-uniform broadcasts; float2 v loads, 512B/wave.
// ---------------------------------------------------------------------------
__global__ __launch_bounds__(512) void k_out(
    const float* __restrict__ vcl, const float* __restrict__ qn,
    const float* __restrict__ wh2, float* __restrict__ out)
{
    __shared__ float q_s[DK * WW];       // 3.5 KB
    __shared__ float weff[WW * WSTR];    // 33.4 KB

    int tid = threadIdx.x;
    // XCD-chunked swizzle: 896 = 8 * 112
    int bid = blockIdx.x;
    int nid = (bid & 7) * 112 + (bid >> 3);
    int b   = nid / 448;
    int rem = nid - b * 448;
    int t   = rem / 56, h = rem - t * 56;
    int pbase = t * (HH * WW) + h * WW;

    for (int i = tid; i < DK * WW; i += 512) {
        int k = i / 56, w = i - k * 56;
        q_s[i] = qn[((size_t)b * DK + k) * S + pbase + w];
    }
    __syncthreads();

    if (tid < 504) {
        int w = tid % 56, q9 = tid / 56;     // 9 tap groups
        float qr[DK];
#pragma unroll
        for (int k = 0; k < DK; ++k) qr[k] = q_s[k * 56 + w];
#pragma unroll 1
        for (int tap = q9; tap < TAPS; tap += 9) {
            float a = 0.f;
#pragma unroll
            for (int k = 0; k < DK; ++k)
                a = fmaf(qr[k], wh2[k * TAPS + tap], a);
            weff[w * WSTR + tap] = a;
        }
    }
    __syncthreads();

    int cc = tid & 63;       // 64 chunks x 2 channels = 128
    int wt = tid >> 6;       // 8 tiles x 7 outputs    = 56
    int wbase = wt * 7;

    const float* vbase = vcl
        + ((size_t)(b * VPT + t) * VPH + h) * VPW * 128
        + (size_t)wbase * 128 + cc * 2;

    float acc[7][2];
#pragma unroll
    for (int k = 0; k < 7; ++k) {
        acc[k][0] = 0.f; acc[k][1] = 0.f;
    }

#pragma unroll 1
    for (int dz = 0; dz < 3; ++dz) {
#pragma unroll 1
        for (int dy = 0; dy < 7; ++dy) {
            const float* vr = vbase + (size_t)((dz * VPH + dy) * VPW) * 128;
            const float* wrow = &weff[wbase * WSTR + (dz * 7 + dy) * 7];
#pragma unroll
            for (int j = 0; j < 13; ++j) {
                float2 A = *reinterpret_cast<const float2*>(vr + j * 128);
                int k0 = (j - 6 > 0) ? (j - 6) : 0;
                int k1 = (j < 6) ? j : 6;
#pragma unroll
                for (int k = 0; k < 7; ++k) {
                    if (k < k0 || k > k1) continue;      // compile-time pruned
                    float wv = wrow[k * WSTR + (j - k)];
                    acc[k][0] = fmaf(wv, A.x, acc[k][0]);
                    acc[k][1] = fmaf(wv, A.y, acc[k][1]);
                }
            }
        }
    }

    size_t ob = ((size_t)b * DV + cc * 2) * S + pbase + wbase;
#pragma unroll
    for (int j = 0; j < 2; ++j)
#pragma unroll
        for (int k = 0; k < 7; ++k)
            out[ob + (size_t)j * S + k] = acc[k][j];
}

// ---------------------------------------------------------------------------
extern "C" void kernel_launch(void* const* d_in, const int* in_sizes, int n_in,
                              void* d_out, int out_size, void* d_ws, size_t ws_size,
                              hipStream_t stream)
{
    const float* x   = (const float*)d_in[0];   // (2,128,8,56,56)
    const float* Wp  = (const float*)d_in[1];   // (144,128)
    const float* wh2 = (const float*)d_in[2];   // (16,1,3,7,7) -> [k][147]
    float* out = (float*)d_out;                 // (2,128,8,56,56)

    float* ws  = (float*)d_ws;
    float* Wpt = ws;                                   //      18,432 floats
    float* qn  = Wpt + (size_t)CIN * NOUT;             //     802,816 floats
    float* vcl = qn  + (size_t)NB * DK * S;            //   9,840,640 floats

    k_twp <<<dim3((CIN * NOUT + 255) / 256), dim3(256), 0, stream>>>(Wp, Wpt);
    k_zero<<<dim3((PCELLS * 32 + 255) / 256), dim3(256), 0, stream>>>(vcl);
    k_proj<<<dim3(NB * S / 64), dim3(576), 0, stream>>>(x, Wpt, qn, vcl);
    k_out <<<dim3(NB * TT * HH), dim3(512), 0, stream>>>(vcl, qn, wh2, out);
}

// Round 7
// 111.070 us; speedup vs baseline: 1.3739x; 1.3739x over previous
//
#include <hip/hip_runtime.h>
#include <hip/hip_bf16.h>

constexpr int NB   = 2;
constexpr int CIN  = 128;
constexpr int TT   = 8;
constexpr int HH   = 56;
constexpr int WW   = 56;
constexpr int S    = TT * HH * WW;      // 25088
constexpr int DK   = 16;
constexpr int DV   = 128;
constexpr int TAPS = 147;               // 3*7*7
constexpr int NOUT = DK + DV;           // 144
// padded channel-last v: [b][t:10][h:62][w:62][c:128]
constexpr int VPT = 10, VPH = 62, VPW = 62;
constexpr int PCELLS = NB * VPT * VPH * VPW;   // 76880 padded cells
constexpr int WSTR = 149;               // weff LDS stride (149 mod 32 = 21 -> conflict-free)
constexpr float EPSf = 1e-6f;

typedef short bf16x8 __attribute__((ext_vector_type(8)));
typedef float f32x4  __attribute__((ext_vector_type(4)));

static __device__ __forceinline__ short f2bf(float f) {
    __hip_bfloat16 h = __float2bfloat16(f);   // RNE
    short s;
    __builtin_memcpy(&s, &h, 2);
    return s;
}

// ---------------------------------------------------------------------------
// k_twp: pack W_proj into MFMA B-fragment order (bf16).
// B[k][n] = Wp[n][k].  Frag (nt, kb): lane l holds B[kb*32+(l>>4)*8+j][nt*16+(l&15)].
// Layout: Wpfrag[((nt*4+kb)*64 + lane)*8 + j]
// ---------------------------------------------------------------------------
__global__ __launch_bounds__(256) void k_twp(
    const float* __restrict__ Wp, short* __restrict__ Wpfrag)
{
    int gid = blockIdx.x * 256 + threadIdx.x;   // < 9*4*64 = 2304
    if (gid >= 9 * 4 * 64) return;
    int lane = gid & 63;
    int kb   = (gid >> 6) & 3;
    int nt   = gid >> 8;
    int n = nt * 16 + (lane & 15);
    int c0 = kb * 32 + (lane >> 4) * 8;
#pragma unroll
    for (int j = 0; j < 8; ++j)
        Wpfrag[(size_t)gid * 8 + j] = f2bf(Wp[n * CIN + c0 + j]);
}

// ---------------------------------------------------------------------------
// Zero only the halo of vcl.
// ---------------------------------------------------------------------------
__global__ __launch_bounds__(256) void k_zero(float* __restrict__ vcl)
{
    int gid  = blockIdx.x * 256 + threadIdx.x;
    int cell = gid >> 5;
    int ch4  = gid & 31;
    if (cell >= PCELLS) return;
    int rb = cell;
    int wp = rb % VPW; rb /= VPW;
    int hp = rb % VPH; rb /= VPH;
    int tp = rb % VPT;
    if (tp >= 1 && tp <= 8 && hp >= 3 && hp <= 58 && wp >= 3 && wp <= 58) return;
    float4 z = {0.f, 0.f, 0.f, 0.f};
    *reinterpret_cast<float4*>(vcl + (size_t)cell * 128 + ch4 * 4) = z;
}

// ---------------------------------------------------------------------------
// k_proj (MFMA): C[p][n] = sum_c x[b][c][p] * Wp[n][c], bf16 inputs, fp32 acc.
// Block = 256 thr = 4 waves; each wave owns 32 positions (2 M-tiles).
// No LDS, no barriers. A-frags gathered per-lane from x (64B-chunk coalesced);
// B-frags from the pre-packed Wpfrag (fully coalesced, L2-hot).
// Epilogue: 16-lane xor-butterfly for ssq/ssv, scaled scatter stores.
// ---------------------------------------------------------------------------
__global__ __launch_bounds__(256) void k_proj(
    const float* __restrict__ x, const short* __restrict__ Wpfrag,
    float* __restrict__ qn, float* __restrict__ vcl)
{
    int tid  = threadIdx.x;
    int lane = tid & 63;
    int wv   = tid >> 6;
    int bid  = blockIdx.x;                 // < NB * S/128 = 392
    int b    = bid / (S / 128);
    int pbas = (bid - b * (S / 128)) * 128 + wv * 32;   // wave's 32 positions

    const float* xb = x + (size_t)b * CIN * S;
    int row = lane & 15;
    int g   = lane >> 4;

    // ---- load A fragments: a[m][kb], lane holds A[row][c = kb*32+g*8+j]
    bf16x8 a[2][4];
#pragma unroll
    for (int m = 0; m < 2; ++m) {
        int p = pbas + m * 16 + row;
#pragma unroll
        for (int kb = 0; kb < 4; ++kb) {
            const float* xs = xb + (size_t)(kb * 32 + g * 8) * S + p;
#pragma unroll
            for (int j = 0; j < 8; ++j)
                a[m][kb][j] = f2bf(xs[(size_t)j * S]);
        }
    }

    // ---- MFMA: acc[m][nt]
    f32x4 acc[2][9];
#pragma unroll
    for (int m = 0; m < 2; ++m)
#pragma unroll
        for (int nt = 0; nt < 9; ++nt) acc[m][nt] = {0.f, 0.f, 0.f, 0.f};

    const bf16x8* bf = reinterpret_cast<const bf16x8*>(Wpfrag);
#pragma unroll
    for (int nt = 0; nt < 9; ++nt) {
#pragma unroll
        for (int kb = 0; kb < 4; ++kb) {
            bf16x8 bfr = bf[(nt * 4 + kb) * 64 + lane];
            acc[0][nt] = __builtin_amdgcn_mfma_f32_16x16x32_bf16(
                a[0][kb], bfr, acc[0][nt], 0, 0, 0);
            acc[1][nt] = __builtin_amdgcn_mfma_f32_16x16x32_bf16(
                a[1][kb], bfr, acc[1][nt], 0, 0, 0);
        }
    }

    // ---- epilogue per m-tile: D[row=4*g+r][col=lane&15]
#pragma unroll
    for (int m = 0; m < 2; ++m) {
        // per-register partial sums of squares
        float sq[4], sv[4];
#pragma unroll
        for (int r = 0; r < 4; ++r) {
            sq[r] = acc[m][0][r] * acc[m][0][r];
            float s = 0.f;
#pragma unroll
            for (int nt = 1; nt < 9; ++nt) s += acc[m][nt][r] * acc[m][nt][r];
            sv[r] = s;
        }
        // butterfly over lane bits 0..3 (sums across the 16 n-columns)
#pragma unroll
        for (int d = 1; d < 16; d <<= 1) {
#pragma unroll
            for (int r = 0; r < 4; ++r) {
                sq[r] += __shfl_xor(sq[r], d, 64);
                sv[r] += __shfl_xor(sv[r], d, 64);
            }
        }
#pragma unroll
        for (int r = 0; r < 4; ++r) {
            int p = pbas + m * 16 + 4 * g + r;
            float qsc = 1.0f / sqrtf(sq[r] + EPSf);
            float vsc = 1.0f / sqrtf(sv[r] + EPSf);
            // q: n = lane&15
            qn[((size_t)b * DK + (lane & 15)) * S + p] = acc[m][0][r] * qsc;
            // v: channel-last padded
            int t  = p / (HH * WW);
            int hw = p - t * (HH * WW);
            int h  = hw / WW;
            int w  = hw - h * WW;
            float* vd = vcl
                + (((size_t)(b * VPT + t + 1) * VPH + (h + 3)) * VPW + (w + 3)) * 128
                + (lane & 15);
#pragma unroll
            for (int nt = 1; nt < 9; ++nt)
                vd[(nt - 1) * 16] = acc[m][nt][r] * vsc;
        }
    }
}

// ---------------------------------------------------------------------------
// k_out: block = (b,t,h) row, 256 threads = 4 waves. (R5 version, verbatim)
// ---------------------------------------------------------------------------
__global__ __launch_bounds__(256) void k_out(
    const float* __restrict__ vcl, const float* __restrict__ qn,
    const float* __restrict__ wh2, float* __restrict__ out)
{
    __shared__ float q_s[DK * WW];       // 3.5 KB
    __shared__ float weff[WW * WSTR];    // 33.4 KB

    int tid = threadIdx.x;
    int bid = blockIdx.x;
    int nid = (bid & 7) * 112 + (bid >> 3);
    int b   = nid / 448;
    int rem = nid - b * 448;
    int t   = rem / 56, h = rem - t * 56;
    int pbase = t * (HH * WW) + h * WW;

    for (int i = tid; i < DK * WW; i += 256) {
        int k = i / 56, w = i - k * 56;
        q_s[i] = qn[((size_t)b * DK + k) * S + pbase + w];
    }
    __syncthreads();

    if (tid < 224) {
        int w = tid % 56, q4 = tid / 56;
        float qr[DK];
#pragma unroll
        for (int k = 0; k < DK; ++k) qr[k] = q_s[k * 56 + w];
#pragma unroll 1
        for (int tap = q4; tap < TAPS; tap += 4) {
            float a = 0.f;
#pragma unroll
            for (int k = 0; k < DK; ++k)
                a = fmaf(qr[k], wh2[k * TAPS + tap], a);
            weff[w * WSTR + tap] = a;
        }
    }
    __syncthreads();

    int cc = tid & 31;       // 32 chunks x 4 channels = 128
    int wt = tid >> 5;       // 8 tiles x 7 outputs    = 56
    int wbase = wt * 7;

    const float* vbase = vcl
        + ((size_t)(b * VPT + t) * VPH + h) * VPW * 128
        + (size_t)wbase * 128 + cc * 4;

    float acc[7][4];
#pragma unroll
    for (int k = 0; k < 7; ++k)
#pragma unroll
        for (int j = 0; j < 4; ++j) acc[k][j] = 0.f;

#pragma unroll 1
    for (int dz = 0; dz < 3; ++dz) {
#pragma unroll 1
        for (int dy = 0; dy < 7; ++dy) {
            const float* vr = vbase + (size_t)((dz * VPH + dy) * VPW) * 128;
            const float* wrow = &weff[wbase * WSTR + (dz * 7 + dy) * 7];
#pragma unroll
            for (int j = 0; j < 13; ++j) {
                float4 A = *reinterpret_cast<const float4*>(vr + j * 128);
                int k0 = (j - 6 > 0) ? (j - 6) : 0;
                int k1 = (j < 6) ? j : 6;
#pragma unroll
                for (int k = 0; k < 7; ++k) {
                    if (k < k0 || k > k1) continue;      // compile-time pruned
                    float wv = wrow[k * WSTR + (j - k)];
                    acc[k][0] = fmaf(wv, A.x, acc[k][0]);
                    acc[k][1] = fmaf(wv, A.y, acc[k][1]);
                    acc[k][2] = fmaf(wv, A.z, acc[k][2]);
                    acc[k][3] = fmaf(wv, A.w, acc[k][3]);
                }
            }
        }
    }

    size_t ob = ((size_t)b * DV + cc * 4) * S + pbase + wbase;
#pragma unroll
    for (int j = 0; j < 4; ++j)
#pragma unroll
        for (int k = 0; k < 7; ++k)
            out[ob + (size_t)j * S + k] = acc[k][j];
}

// ---------------------------------------------------------------------------
extern "C" void kernel_launch(void* const* d_in, const int* in_sizes, int n_in,
                              void* d_out, int out_size, void* d_ws, size_t ws_size,
                              hipStream_t stream)
{
    const float* x   = (const float*)d_in[0];   // (2,128,8,56,56)
    const float* Wp  = (const float*)d_in[1];   // (144,128)
    const float* wh2 = (const float*)d_in[2];   // (16,1,3,7,7) -> [k][147]
    float* out = (float*)d_out;                 // (2,128,8,56,56)

    float* ws     = (float*)d_ws;
    short* Wpfrag = (short*)ws;                        //  18,432 shorts (9,216 floats)
    float* qn     = ws + 9216;                         // NB*DK*S    =   802,816
    float* vcl    = qn + (size_t)NB * DK * S;          // NB*VPT*VPH*VPW*128 = 19.7M

    k_twp <<<dim3(9), dim3(256), 0, stream>>>(Wp, Wpfrag);
    k_zero<<<dim3((PCELLS * 32 + 255) / 256), dim3(256), 0, stream>>>(vcl);
    k_proj<<<dim3(NB * S / 128), dim3(256), 0, stream>>>(x, Wpfrag, qn, vcl);
    k_out <<<dim3(NB * TT * HH), dim3(256), 0, stream>>>(vcl, qn, wh2, out);
}